// Round 6
// baseline (131.042 us; speedup 1.0000x reference)
//
#include <hip/hip_runtime.h>
#include <stdint.h>

// Problem dims (fixed by reference): E=16, B=8, S=2048, D=2048
#define N_TOK   16384          // B*S
#define D_MODEL 2048
#define N_EXP   16
#define CAP     1024           // N_TOK / N_EXP
#define TOTAL   (N_TOK * D_MODEL)        // 33,554,432 elements

#define BLK_TOK 8              // token rows per block
#define THREADS 256
#define STEPS   16             // float4 groups per thread (8 rows x 512 f4 / 256 thr)
#define NBLK    (N_TOK / BLK_TOK)        // 2048 blocks = 8192 waves = 32/CU exactly

// keep  <=>  u < 0.9f  <=>  (bits >> 9) < 7549747  <=>  bits < 7549747<<9
// (0.9f == 7549747*2^-23 exactly; floor-shift makes the forms equivalent)
#define KEEP_THR_SH 0xE6666600u

// ---------------------------------------------------------------------------
// rotl forced to a single v_alignbit_b32: rotl(x,r) == {x,x} >> (32-r).
// 32-r in {3,6,8,15,16,17,19,26} -> all valid VOP3 inline constants.
// ---------------------------------------------------------------------------
template <int R>
__device__ __forceinline__ uint32_t rotl(uint32_t x) {
    uint32_t d;
    asm("v_alignbit_b32 %0, %1, %1, %2" : "=v"(d) : "v"(x), "n"(32 - R));
    return d;
}

// ---------------------------------------------------------------------------
// Threefry-2x32, 20 rounds, key = (0, 42) == jax.random.key(42).
// Partitionable path: counter = (0, i); 32-bit draw = XOR-fold x0 ^ x1.
// ---------------------------------------------------------------------------
__device__ __forceinline__ uint32_t tf_bits(uint32_t i) {
    const uint32_t k0 = 0u;
    const uint32_t k1 = 42u;
    const uint32_t k2 = 0x1BD11BDAu ^ 0u ^ 42u;
    uint32_t x0 = 0u + k0;        // counter hi = 0
    uint32_t x1 = i + k1;         // counter lo = i
#define TF_R(r) { x0 += x1; x1 = rotl<r>(x1) ^ x0; }
    TF_R(13) TF_R(15) TF_R(26) TF_R(6)
    x0 += k1; x1 += k2 + 1u;
    TF_R(17) TF_R(29) TF_R(16) TF_R(24)
    x0 += k2; x1 += k0 + 2u;
    TF_R(13) TF_R(15) TF_R(26) TF_R(6)
    x0 += k0; x1 += k1 + 3u;
    TF_R(17) TF_R(29) TF_R(16) TF_R(24)
    x0 += k1; x1 += k2 + 4u;
    TF_R(13) TF_R(15) TF_R(26) TF_R(6)
    x0 += k2; x1 += k0 + 5u;
#undef TF_R
    return x0 ^ x1;               // XOR-fold (partitionable sub-64 narrowing)
}

// ---------------------------------------------------------------------------
// Kernel 1: within-expert rank. One block (1 wave) per expert; int4 route
// loads (256 tokens/iter) + wave shuffle-scan of per-lane match counts.
// srcrow[t] = routes[t]*CAP + rank(t)
// ---------------------------------------------------------------------------
__global__ __launch_bounds__(64) void rank_kernel(const int* __restrict__ routes,
                                                  int* __restrict__ srcrow) {
    const int e    = blockIdx.x;     // expert id
    const int lane = threadIdx.x;    // 0..63
    const int4* routes4 = (const int4*)routes;
    int running = 0;
    for (int base = 0; base < N_TOK / 4; base += 64) {
        int4 r = routes4[base + lane];
        int m0 = (r.x == e), m1 = (r.y == e), m2 = (r.z == e), m3 = (r.w == e);
        int cnt = m0 + m1 + m2 + m3;
        int pre = cnt;
        #pragma unroll
        for (int dlt = 1; dlt < 64; dlt <<= 1) {
            int up = __shfl_up(pre, dlt);
            if (lane >= dlt) pre += up;
        }
        int excl = pre - cnt;                 // matches in earlier lanes
        int tot  = __shfl(pre, 63);           // matches in whole chunk
        int t0 = (base + lane) * 4;
        int p = running + excl;
        if (m0) { srcrow[t0 + 0] = e * CAP + p; p++; }
        if (m1) { srcrow[t0 + 1] = e * CAP + p; p++; }
        if (m2) { srcrow[t0 + 2] = e * CAP + p; p++; }
        if (m3) { srcrow[t0 + 3] = e * CAP + p; p++; }
        running += tot;
    }
}

// ---------------------------------------------------------------------------
// Kernel 2: combine + dropout + residual, software-pipelined.
// Block = 8 token rows (4096 float4), 256 threads, 16 float4 steps/thread.
// Step k's token (= 8*b + k/2) is block-uniform -> srcrow/rpm scalarize.
// Loads for step k+1 issue before threefry of step k (latency hides under
// the ~600-cycle VALU burst instead of serializing after it).
// ---------------------------------------------------------------------------
__global__ __launch_bounds__(THREADS) void combine_kernel(
        const float4* __restrict__ hidden,
        const float4* __restrict__ eo4,
        const int*    __restrict__ srcrow,
        const float*  __restrict__ rpm,
        float4*       __restrict__ out) {
    const int b     = blockIdx.x;
    const int tid   = threadIdx.x;                 // 0..255
    const int t0    = b * BLK_TOK;
    const int gbase = b * (BLK_TOK * 512);         // first float4 of block

    // Block-uniform per-row scalars (compiler scalarizes to s_load)
    int   r[BLK_TOK];
    float sc[BLK_TOK];
    #pragma unroll
    for (int q = 0; q < BLK_TOK; ++q) {
        r[q]  = srcrow[t0 + q];
        sc[q] = rpm[t0 + q] * (1.0f / 0.9f);
    }

    // Software pipeline
    float4 h = hidden[gbase + tid];
    float4 e = eo4[(r[0] << 9) + tid];

    #pragma unroll
    for (int k = 0; k < STEPS; ++k) {
        float4 hn, en;
        if (k + 1 < STEPS) {
            const int idx = (k + 1) * THREADS + tid;       // within-block f4 idx
            hn = hidden[gbase + idx];
            en = eo4[(r[(k + 1) >> 1] << 9) + (idx & 511)];
        }

        const uint32_t j = (uint32_t)(gbase + k * THREADS + tid) << 2;
        const uint32_t b0 = tf_bits(j + 0);
        const uint32_t b1 = tf_bits(j + 1);
        const uint32_t b2 = tf_bits(j + 2);
        const uint32_t b3 = tf_bits(j + 3);

        const float s = sc[k >> 1];
        const float m0 = (b0 < KEEP_THR_SH) ? s : 0.0f;
        const float m1 = (b1 < KEEP_THR_SH) ? s : 0.0f;
        const float m2 = (b2 < KEEP_THR_SH) ? s : 0.0f;
        const float m3 = (b3 < KEEP_THR_SH) ? s : 0.0f;

        float4 o;
        o.x = fmaf(m0, e.x, h.x);
        o.y = fmaf(m1, e.y, h.y);
        o.z = fmaf(m2, e.z, h.z);
        o.w = fmaf(m3, e.w, h.w);
        out[gbase + k * THREADS + tid] = o;

        h = hn; e = en;
    }
}

// ---------------------------------------------------------------------------
extern "C" void kernel_launch(void* const* d_in, const int* in_sizes, int n_in,
                              void* d_out, int out_size, void* d_ws, size_t ws_size,
                              hipStream_t stream) {
    const float* hidden = (const float*)d_in[0];   // [B,S,D] f32
    const float* eo     = (const float*)d_in[1];   // [E,CAP,D] f32
    const int*   routes = (const int*)d_in[2];     // [N] i32
    const float* rpm    = (const float*)d_in[3];   // [N] f32

    int* srcrow = (int*)d_ws;                      // N_TOK ints = 64 KB scratch

    rank_kernel<<<N_EXP, 64, 0, stream>>>(routes, srcrow);
    combine_kernel<<<NBLK, THREADS, 0, stream>>>(
        (const float4*)hidden, (const float4*)eo, srcrow, rpm, (float4*)d_out);
}